// Round 5
// baseline (2933.382 us; speedup 1.0000x reference)
//
#include <hip/hip_runtime.h>
#include <hip/hip_bf16.h>
#include <stdint.h>

typedef __attribute__((ext_vector_type(8))) short short8;
typedef __attribute__((ext_vector_type(4))) float floatx4;
typedef __attribute__((ext_vector_type(4))) int intx4;
typedef __attribute__((ext_vector_type(4))) unsigned int uintx4;
typedef __attribute__((ext_vector_type(4))) unsigned short ushort4v;

#define DEVI __device__ __forceinline__

// ---- problem sizes ----
constexpr int B_ = 256, T_ = 512, D_ = 128, H_ = 512, C_ = 10;
constexpr int KTOT = H_ + D_;       // 640: k = [h(512) ; x(128)]
constexpr int RG = 16;              // batch rows per group
constexpr int NBG = 16;             // batch groups
constexpr int NCG = 16;             // column groups
constexpr int HCW = 32;             // h-cols per WG

// ---- workspace layout (bytes) ----
constexpr size_t OFF_XB = 0;
constexpr size_t SZ_XB  = (size_t)B_ * T_ * D_ * 2;          // x in bf16
constexpr size_t OFF_WC = OFF_XB + SZ_XB;
constexpr size_t SZ_WC  = (size_t)4 * H_ * KTOT * 2;         // Wcomb[4*H][640] bf16
constexpr size_t OFF_HB = OFF_WC + SZ_WC;
constexpr size_t SZ_HB  = (size_t)2 * B_ * H_ * 4;           // h double buffer: u32 = (bf16<<16)|epoch
constexpr size_t OFF_CT = OFF_HB + SZ_HB;
constexpr size_t SZ_CT  = (size_t)NBG * (T_ + 1) * 4;        // gate-hint counters
constexpr size_t WS_NEED = OFF_CT + SZ_CT;

DEVI uint16_t f2bf(float f) {
    uint32_t u = __builtin_bit_cast(uint32_t, f);
    u += 0x7FFFu + ((u >> 16) & 1u);
    return (uint16_t)(u >> 16);
}
DEVI float bf2f(uint16_t u) {
    return __builtin_bit_cast(float, (uint32_t)u << 16);
}
DEVI float sigf(float x)  { return 1.0f / (1.0f + __expf(-x)); }
DEVI float tanhf_(float x){ return 1.0f - 2.0f / (1.0f + __expf(2.0f * x)); }

// ---- prep: x fp32 -> bf16 ----
__global__ void k_cvt_x(const float* __restrict__ x, uint16_t* __restrict__ xb) {
    int i = (blockIdx.x * 256 + threadIdx.x) * 4;   // total B*T*D = 16777216
    float4 v = *reinterpret_cast<const float4*>(x + i);
    ushort4v o;
    o.x = f2bf(v.x); o.y = f2bf(v.y); o.z = f2bf(v.z); o.w = f2bf(v.w);
    *reinterpret_cast<ushort4v*>(xb + i) = o;
}

// ---- prep: build combined transposed bf16 weights Wcomb[n'=g*512+n][k] ----
__global__ void k_build_w(const float* __restrict__ wgh, const float* __restrict__ wih,
                          const float* __restrict__ wfh, const float* __restrict__ woh,
                          const float* __restrict__ wgx, const float* __restrict__ wix,
                          const float* __restrict__ wfx, const float* __restrict__ wox,
                          uint16_t* __restrict__ wc) {
    int np = blockIdx.x;            // 0..2047
    int g = np >> 9, n = np & 511;
    const float* wh = (g == 0) ? wgh : (g == 1) ? wih : (g == 2) ? wfh : woh;
    const float* wx = (g == 0) ? wgx : (g == 1) ? wix : (g == 2) ? wfx : wox;
    for (int k = threadIdx.x; k < KTOT; k += 256) {
        float v = (k < H_) ? wh[(size_t)k * H_ + n] : wx[(size_t)(k - H_) * H_ + n];
        wc[(size_t)np * KTOT + k] = f2bf(v);
    }
}

// issue one cache-bypassing (device-coherent) 16B load at byte offset IMM
#define PLOAD(dst, base, IMM) \
    asm volatile("global_load_dwordx4 %0, %1, off offset:" #IMM " sc0 sc1" \
                 : "=v"(dst) : "v"(base) : "memory")

// ---- main recurrent kernel ----
// WG = 16 batch rows x 32 h-cols; wave = all 4 gates for 8 cols
// (tile0 cols = [g|i], tile1 cols = [f|o]); gate exchange = shfl_xor(8).
// h exchange: u32 words (bf16(h)<<16 | epoch). Sync = counter GATE (hint,
// tid0-only poll) + per-word epoch VERIFY (correctness). Producer signals
// right after store issue -- no vmcnt drain on the critical path.
__global__ __launch_bounds__(256, 1) void k_lstm(
    const uint16_t* __restrict__ xb,   // [B][T][D] bf16
    const uint16_t* __restrict__ wc,   // [4H][KTOT] bf16
    const float* __restrict__ bgp, const float* __restrict__ bip,
    const float* __restrict__ bfp, const float* __restrict__ bop,
    uint32_t* hbuf,                    // [2][B][H] packed (bf16<<16)|epoch
    int* counters)                     // [NBG][T+1] gate hints
{
    __shared__ __align__(16) short hx[RG * KTOT];                 // 20 KB, XOR-swizzled

    const int tid  = threadIdx.x;
    const int lane = tid & 63;
    const int w    = tid >> 6;          // wave id -> col sub-block w*8
    const int bid  = blockIdx.x;
    // keep each batch-group's 16 WGs on one XCD (perf heuristic only)
    const int xcd = bid & 7, j = bid >> 3;
    const int bg = xcd * 2 + (j >> 4);
    const int cg = j & 15;
    const int b0  = bg * RG;
    const int hc0 = cg * HCW;

    // ---- load this wave's weight slice into registers ----
    // B-frag: col = lane&15, k = (lane>>4)*8 + j
    short8 bf0[20], bf1[20];
    {
        const int lcol = lane & 15, kgrp = lane >> 4;
        const int cw = lcol & 7, hi = lcol >> 3;
        const int colg = hc0 + w * 8 + cw;
        const size_t row0 = (size_t)((0 + hi) * H_ + colg) * KTOT;  // g or i
        const size_t row1 = (size_t)((2 + hi) * H_ + colg) * KTOT;  // f or o
        #pragma unroll
        for (int ks = 0; ks < 20; ++ks) {
            bf0[ks] = *reinterpret_cast<const short8*>(wc + row0 + kgrp * 8 + ks * 32);
            bf1[ks] = *reinterpret_cast<const short8*>(wc + row1 + kgrp * 8 + ks * 32);
        }
        #pragma unroll
        for (int ks = 0; ks < 20; ++ks) {
            asm volatile("" : "+v"(bf0[ks]));
            asm volatile("" : "+v"(bf1[ks]));
        }
    }

    // per-lane cell column; lo lanes do rows +0,+1 of their row-group, hi rows +2,+3
    const int cl    = lane & 7;
    const int mycol = hc0 + w * 8 + cl;
    const bool lo   = (lane & 8) == 0;
    const int rowb  = (lane >> 4) * 4 + (lo ? 0 : 2);
    const float bgv = bgp[mycol], biv = bip[mycol], bfv = bfp[mycol], bov = bop[mycol];
    float cst[2] = {0.f, 0.f};

    // staging mapping: thread -> (row, 32-word chunk)
    const int srow = tid >> 4, sseg = tid & 15;
    const int sswz = (srow & 7) << 4;
    // A-fragment base (mfma 16x16x32: row = lane&15, k = (lane>>4)*8 + j)
    const int arow = lane & 15, akg = lane >> 4;
    const int abase = arow * (KTOT * 2) + akg * 16;
    const int aswz  = (arow & 7) << 4;

    int* ctr = counters + bg * (T_ + 1);
    char* lds = (char*)hx;

    for (int t = 0; t < T_; ++t) {
        // ---- stage x part (cols 512..639) first: no h dependence ----
        {
            const short8 xv = *reinterpret_cast<const short8*>(
                xb + ((size_t)(b0 + srow) * T_ + t) * D_ + sseg * 8);
            int byte = srow * (KTOT * 2) + H_ * 2 + sseg * 16;
            *reinterpret_cast<short8*>(lds + (byte ^ sswz)) = xv;
        }

        if (t == 0) {
            intx4 z = {0, 0, 0, 0};
            #pragma unroll
            for (int c4 = 0; c4 < 4; ++c4) {
                int byte = srow * (KTOT * 2) + sseg * 64 + c4 * 16;
                *reinterpret_cast<intx4*>(lds + (byte ^ sswz)) = z;
            }
        } else {
            // ---- GATE: tid0 polls the per-bg counter (cheap hint, 4B load) ----
            if (tid == 0) {
                int it = 0;
                while (__hip_atomic_load(ctr + t, __ATOMIC_RELAXED, __HIP_MEMORY_SCOPE_AGENT) < NCG) {
                    if (++it > (1 << 22)) break;   // fail loud, not hang
                }
                asm volatile("" ::: "memory");
            }
            __syncthreads();

            // ---- VERIFY + load: one bulk pass, epoch-checked per word ----
            const uint32_t* src = hbuf + (size_t)(t & 1) * B_ * H_
                                       + (size_t)(b0 + srow) * H_ + sseg * 32;
            uintx4 v0, v1, v2, v3, v4, v5, v6, v7;
            const uint32_t ep = (uint32_t)t;
            int it = 0;
            for (;;) {
                PLOAD(v0, src,   0); PLOAD(v1, src,  16);
                PLOAD(v2, src,  32); PLOAD(v3, src,  48);
                PLOAD(v4, src,  64); PLOAD(v5, src,  80);
                PLOAD(v6, src,  96); PLOAD(v7, src, 112);
                asm volatile("s_waitcnt vmcnt(0)" ::: "memory");
                uint32_t d = 0;
                #pragma unroll
                for (int e = 0; e < 4; ++e) {
                    d |= (v0[e] ^ ep); d |= (v1[e] ^ ep);
                    d |= (v2[e] ^ ep); d |= (v3[e] ^ ep);
                    d |= (v4[e] ^ ep); d |= (v5[e] ^ ep);
                    d |= (v6[e] ^ ep); d |= (v7[e] ^ ep);
                }
                if ((d & 0xFFFFu) == 0) break;
                if (++it > (1 << 20)) break;    // fail loud, not hang
            }
            // ---- unpack (hi16 of each word) into bf16 pairs, write swizzled LDS ----
            uintx4 pr[2];
            pr[0].x = (v0.x >> 16) | (v0.y & 0xFFFF0000u);
            pr[0].y = (v0.z >> 16) | (v0.w & 0xFFFF0000u);
            pr[0].z = (v1.x >> 16) | (v1.y & 0xFFFF0000u);
            pr[0].w = (v1.z >> 16) | (v1.w & 0xFFFF0000u);
            pr[1].x = (v2.x >> 16) | (v2.y & 0xFFFF0000u);
            pr[1].y = (v2.z >> 16) | (v2.w & 0xFFFF0000u);
            pr[1].z = (v3.x >> 16) | (v3.y & 0xFFFF0000u);
            pr[1].w = (v3.z >> 16) | (v3.w & 0xFFFF0000u);
            #pragma unroll
            for (int c4 = 0; c4 < 2; ++c4) {
                int byte = srow * (KTOT * 2) + sseg * 64 + c4 * 16;
                *reinterpret_cast<uintx4*>(lds + (byte ^ sswz)) = pr[c4];
            }
            pr[0].x = (v4.x >> 16) | (v4.y & 0xFFFF0000u);
            pr[0].y = (v4.z >> 16) | (v4.w & 0xFFFF0000u);
            pr[0].z = (v5.x >> 16) | (v5.y & 0xFFFF0000u);
            pr[0].w = (v5.z >> 16) | (v5.w & 0xFFFF0000u);
            pr[1].x = (v6.x >> 16) | (v6.y & 0xFFFF0000u);
            pr[1].y = (v6.z >> 16) | (v6.w & 0xFFFF0000u);
            pr[1].z = (v7.x >> 16) | (v7.y & 0xFFFF0000u);
            pr[1].w = (v7.z >> 16) | (v7.w & 0xFFFF0000u);
            #pragma unroll
            for (int c4 = 0; c4 < 2; ++c4) {
                int byte = srow * (KTOT * 2) + sseg * 64 + (2 + c4) * 16;
                *reinterpret_cast<uintx4*>(lds + (byte ^ sswz)) = pr[c4];
            }
        }
        __syncthreads();

        // ---- MFMA: [16 rows x 16 cols] x 2 tiles, K = 640 ----
        floatx4 acc0 = {0.f, 0.f, 0.f, 0.f}, acc1 = {0.f, 0.f, 0.f, 0.f};
        #pragma unroll
        for (int ks = 0; ks < 20; ++ks) {
            int byte = (abase + ks * 64) ^ aswz;
            short8 a = *reinterpret_cast<const short8*>(lds + byte);
            acc0 = __builtin_amdgcn_mfma_f32_16x16x32_bf16(a, bf0[ks], acc0, 0, 0, 0);
            acc1 = __builtin_amdgcn_mfma_f32_16x16x32_bf16(a, bf1[ks], acc1, 0, 0, 0);
        }

        // ---- gate exchange in-wave (C layout: col=lane&15, row=(lane>>4)*4+r) ----
        float q0[4], q1[4];
        #pragma unroll
        for (int r = 0; r < 4; ++r) {
            q0[r] = __shfl_xor(acc0[r], 8, 64);
            q1[r] = __shfl_xor(acc1[r], 8, 64);
        }
        const uint32_t epn = (uint32_t)(t + 1);
        uint32_t* hdst = hbuf + (size_t)((t + 1) & 1) * B_ * H_
                              + (size_t)(b0 + rowb) * H_ + mycol;
        #pragma unroll
        for (int e = 0; e < 2; ++e) {
            // lo lane processes rows rb+e with r=e; hi lane r=2+e (static indices)
            float pg = lo ? acc0[e] : q0[2 + e];
            float pi = lo ? q0[e]   : acc0[2 + e];
            float pf = lo ? acc1[e] : q1[2 + e];
            float po = lo ? q1[e]   : acc1[2 + e];
            float g = tanhf_(pg + bgv), ii = sigf(pi + biv);
            float f = sigf(pf + bfv),   o  = sigf(po + bov);
            float c = g * ii + cst[e] * f;
            cst[e] = c;
            uint32_t word = ((uint32_t)f2bf(tanhf_(c) * o) << 16) | epn;
            __hip_atomic_store(hdst + (size_t)e * H_, word,
                               __ATOMIC_RELAXED, __HIP_MEMORY_SCOPE_AGENT);
        }
        // NO vmcnt drain: the counter is only a gate hint; consumers verify
        // per-word epochs. Barrier = all threads have ISSUED their stores
        // (and finished reading LDS), then tid0 signals.
        __syncthreads();
        if (tid == 0)
            __hip_atomic_fetch_add(ctr + t + 1, 1, __ATOMIC_RELAXED, __HIP_MEMORY_SCOPE_AGENT);
    }
}

// ---- final projection: out[b][c] = h_T[b] . wph[:,c] + bp[c] ----
// h_T has epoch 512 and lives in buffer parity 0; words = (bf16<<16)|epoch.
__global__ void k_proj(const uint32_t* __restrict__ hb0, const float* __restrict__ wph,
                       const float* __restrict__ bp, float* __restrict__ out) {
    int b = blockIdx.x, lane = threadIdx.x;     // 64 threads
    const uint32_t* hrow = hb0 + (size_t)b * H_;
    float p[C_];
    #pragma unroll
    for (int c = 0; c < C_; ++c) p[c] = 0.f;
    #pragma unroll
    for (int q = 0; q < 8; ++q) {
        int k = lane + q * 64;
        uint32_t u = __hip_atomic_load(hrow + k, __ATOMIC_RELAXED, __HIP_MEMORY_SCOPE_AGENT);
        float hv = bf2f((uint16_t)(u >> 16));
        #pragma unroll
        for (int c = 0; c < C_; ++c)
            p[c] += hv * wph[(size_t)k * C_ + c];
    }
    #pragma unroll
    for (int c = 0; c < C_; ++c) {
        float v = p[c];
        #pragma unroll
        for (int off = 32; off; off >>= 1) v += __shfl_down(v, off, 64);
        if (lane == 0) out[(size_t)b * C_ + c] = v + bp[c];
    }
}

extern "C" void kernel_launch(void* const* d_in, const int* in_sizes, int n_in,
                              void* d_out, int out_size, void* d_ws, size_t ws_size,
                              hipStream_t stream) {
    const float* x   = (const float*)d_in[0];
    const float* wgx = (const float*)d_in[1];
    const float* wgh = (const float*)d_in[2];
    const float* bg  = (const float*)d_in[3];
    const float* wix = (const float*)d_in[4];
    const float* wih = (const float*)d_in[5];
    const float* bi  = (const float*)d_in[6];
    const float* wfx = (const float*)d_in[7];
    const float* wfh = (const float*)d_in[8];
    const float* bf  = (const float*)d_in[9];
    const float* wox = (const float*)d_in[10];
    const float* woh = (const float*)d_in[11];
    const float* bo  = (const float*)d_in[12];
    const float* wph = (const float*)d_in[13];
    const float* bp  = (const float*)d_in[14];

    if (ws_size < WS_NEED) return;  // fail loud (wrong output) rather than corrupt

    char* ws = (char*)d_ws;
    uint16_t* xbp = (uint16_t*)(ws + OFF_XB);
    uint16_t* wcp = (uint16_t*)(ws + OFF_WC);
    uint32_t* hbp = (uint32_t*)(ws + OFF_HB);
    int*      ctp = (int*)(ws + OFF_CT);

    hipMemsetAsync(ctp, 0, SZ_CT, stream);
    k_cvt_x<<<(B_ * T_ * D_) / (256 * 4), 256, 0, stream>>>(x, xbp);
    k_build_w<<<4 * H_, 256, 0, stream>>>(wgh, wih, wfh, woh, wgx, wix, wfx, wox, wcp);
    k_lstm<<<256, 256, 0, stream>>>(xbp, wcp, bg, bi, bf, bo, hbp, ctp);
    k_proj<<<B_, 64, 0, stream>>>(hbp /* parity 0 holds h_T (epoch 512) */, wph, bp, (float*)d_out);
}

// Round 6
// 1619.916 us; speedup vs baseline: 1.8108x; 1.8108x over previous
//
#include <hip/hip_runtime.h>
#include <hip/hip_bf16.h>
#include <stdint.h>

typedef __attribute__((ext_vector_type(8))) short short8;
typedef __attribute__((ext_vector_type(4))) float floatx4;
typedef __attribute__((ext_vector_type(4))) int intx4;
typedef __attribute__((ext_vector_type(2))) unsigned long long ull2;
typedef __attribute__((ext_vector_type(4))) unsigned short ushort4v;

#define DEVI __device__ __forceinline__

// ---- problem sizes ----
constexpr int B_ = 256, T_ = 512, D_ = 128, H_ = 512, C_ = 10;
constexpr int KTOT = H_ + D_;       // 640: k = [h(512) ; x(128)]
constexpr int RG = 16;              // batch rows per group
constexpr int NBG = 16;             // batch groups
constexpr int NCG = 16;             // column groups
constexpr int HCW = 32;             // h-cols per WG

// ---- workspace layout (bytes) ----
constexpr size_t OFF_XB = 0;
constexpr size_t SZ_XB  = (size_t)B_ * T_ * D_ * 2;          // x in bf16
constexpr size_t OFF_WC = OFF_XB + SZ_XB;
constexpr size_t SZ_WC  = (size_t)4 * H_ * KTOT * 2;         // Wcomb[4*H][640] bf16 (transposed)
constexpr size_t OFF_HB = OFF_WC + SZ_WC;
constexpr size_t SZ_HB  = (size_t)2 * B_ * H_ * 2;           // h double buffer bf16
constexpr size_t OFF_CT = OFF_HB + SZ_HB;
constexpr size_t SZ_CT  = (size_t)NBG * (T_ + 1) * 4;        // sync counters
constexpr size_t WS_NEED = OFF_CT + SZ_CT;

DEVI uint16_t f2bf(float f) {
    uint32_t u = __builtin_bit_cast(uint32_t, f);
    u += 0x7FFFu + ((u >> 16) & 1u);
    return (uint16_t)(u >> 16);
}
DEVI float bf2f(uint16_t u) {
    return __builtin_bit_cast(float, (uint32_t)u << 16);
}
DEVI float sigf(float x)  { return 1.0f / (1.0f + __expf(-x)); }
DEVI float tanhf_(float x){ return 1.0f - 2.0f / (1.0f + __expf(2.0f * x)); }

// ---- prep: x fp32 -> bf16 ----
__global__ void k_cvt_x(const float* __restrict__ x, uint16_t* __restrict__ xb) {
    int i = (blockIdx.x * 256 + threadIdx.x) * 4;   // total B*T*D = 16777216
    float4 v = *reinterpret_cast<const float4*>(x + i);
    ushort4v o;
    o.x = f2bf(v.x); o.y = f2bf(v.y); o.z = f2bf(v.z); o.w = f2bf(v.w);
    *reinterpret_cast<ushort4v*>(xb + i) = o;
}

// ---- prep: build combined transposed bf16 weights Wcomb[n'=g*512+n][k] ----
//  k<512 : W?h[k][n] ;  k>=512 : W?x[k-512][n]
__global__ void k_build_w(const float* __restrict__ wgh, const float* __restrict__ wih,
                          const float* __restrict__ wfh, const float* __restrict__ woh,
                          const float* __restrict__ wgx, const float* __restrict__ wix,
                          const float* __restrict__ wfx, const float* __restrict__ wox,
                          uint16_t* __restrict__ wc) {
    int np = blockIdx.x;            // 0..2047
    int g = np >> 9, n = np & 511;
    const float* wh = (g == 0) ? wgh : (g == 1) ? wih : (g == 2) ? wfh : woh;
    const float* wx = (g == 0) ? wgx : (g == 1) ? wix : (g == 2) ? wfx : wox;
    for (int k = threadIdx.x; k < KTOT; k += 256) {
        float v = (k < H_) ? wh[(size_t)k * H_ + n] : wx[(size_t)(k - H_) * H_ + n];
        wc[(size_t)np * KTOT + k] = f2bf(v);
    }
}

// Opaque 16B weight load: asm result cannot be rematerialized, so the
// compiler MUST keep it resident in VGPRs for the whole kernel.
#define WLOAD(dst, base, IMM) \
    asm volatile("global_load_dwordx4 %0, %1, off offset:" #IMM \
                 : "=v"(dst) : "v"(base))
#define WLOAD20(arr, base) \
    WLOAD(arr[0],  base, 0);    WLOAD(arr[1],  base, 64);   \
    WLOAD(arr[2],  base, 128);  WLOAD(arr[3],  base, 192);  \
    WLOAD(arr[4],  base, 256);  WLOAD(arr[5],  base, 320);  \
    WLOAD(arr[6],  base, 384);  WLOAD(arr[7],  base, 448);  \
    WLOAD(arr[8],  base, 512);  WLOAD(arr[9],  base, 576);  \
    WLOAD(arr[10], base, 640);  WLOAD(arr[11], base, 704);  \
    WLOAD(arr[12], base, 768);  WLOAD(arr[13], base, 832);  \
    WLOAD(arr[14], base, 896);  WLOAD(arr[15], base, 960);  \
    WLOAD(arr[16], base, 1024); WLOAD(arr[17], base, 1088); \
    WLOAD(arr[18], base, 1152); WLOAD(arr[19], base, 1216)

// ---- main recurrent kernel ----
__global__ __launch_bounds__(256, 1) void k_lstm(
    const uint16_t* __restrict__ xb,   // [B][T][D] bf16
    const uint16_t* __restrict__ wc,   // [4H][KTOT] bf16
    const float* __restrict__ bgp, const float* __restrict__ bip,
    const float* __restrict__ bfp, const float* __restrict__ bop,
    uint16_t* hbuf,                    // [2][B][H] bf16
    int* counters)                     // [NBG][T+1]
{
    __shared__ __align__(16) short hx[RG * KTOT];                 // 20 KB, XOR-swizzled
    __shared__ float pre[4][RG][HCW + 1];                         // 8448 B

    const int tid  = threadIdx.x;
    const int lane = tid & 63;
    const int w    = tid >> 6;          // wave id == gate id (g,i,f,o)
    const int bid  = blockIdx.x;
    // keep each batch-group's 16 WGs on one XCD (perf heuristic only)
    const int xcd = bid & 7, j = bid >> 3;
    const int bg = xcd * 2 + (j >> 4);
    const int cg = j & 15;
    const int b0  = bg * RG;
    const int hc0 = cg * HCW;

    // ---- load this wave's weight slice into registers (PINNED: asm loads) ----
    short8 bfr0[20], bfr1[20];
    {
        const int lcol = lane & 15, kgrp = lane >> 4;
        const uint16_t* src0 = wc + (size_t)(w * H_ + hc0 + 0  + lcol) * KTOT + kgrp * 8;
        const uint16_t* src1 = wc + (size_t)(w * H_ + hc0 + 16 + lcol) * KTOT + kgrp * 8;
        WLOAD20(bfr0, src0);
        WLOAD20(bfr1, src1);
        asm volatile("s_waitcnt vmcnt(0)" ::: "memory");
    }

    // ---- elementwise thread mapping: (row, col pair) fixed for whole run ----
    const int erow = tid >> 4;          // 0..15
    const int ep   = tid & 15;          // 0..15 -> cols ep*2, ep*2+1
    const int hcg0 = hc0 + ep * 2;
    float bge[2], bie[2], bfe[2], boe[2], cst[2] = {0.f, 0.f};
    #pragma unroll
    for (int e = 0; e < 2; ++e) {
        bge[e] = bgp[hcg0 + e]; bie[e] = bip[hcg0 + e];
        bfe[e] = bfp[hcg0 + e]; boe[e] = bop[hcg0 + e];
    }

    // staging mapping: thread -> (row, 64B segment)
    const int srow = tid >> 4, sseg = tid & 15;
    const int sswz = (srow & 7) << 4;
    // A-fragment base (mfma 16x16x32: row = lane&15, k = (lane>>4)*8 + j)
    const int arow = lane & 15, akg = lane >> 4;
    const int abase = arow * (KTOT * 2) + akg * 16;
    const int aswz  = (arow & 7) << 4;
    // h store base row for this lane's 4 rows
    const int hrow0 = (lane >> 4) * 4;

    int* ctr = counters + bg * (T_ + 1);
    char* lds = (char*)hx;

    for (int t = 0; t < T_; ++t) {
        // ---- stage x part (cols 512..639) BEFORE the wait (no h dependence;
        //      prev step's LDS readers passed the post-store barrier) ----
        {
            const short8 xv = *reinterpret_cast<const short8*>(
                xb + ((size_t)(b0 + srow) * T_ + t) * D_ + sseg * 8);
            int byte = srow * (KTOT * 2) + H_ * 2 + sseg * 16;
            *reinterpret_cast<short8*>(lds + (byte ^ sswz)) = xv;
        }

        // ---- wait for h_t from all 16 column groups (RELAXED poll) ----
        if (t > 0) {
            if (tid == 0) {
                int it = 0;
                while (__hip_atomic_load(ctr + t, __ATOMIC_RELAXED, __HIP_MEMORY_SCOPE_AGENT) < NCG) {
                    if (++it > (1 << 28)) break;   // safety: fail loud, not hang
                    __builtin_amdgcn_s_sleep(1);
                }
                asm volatile("" ::: "memory");     // compiler reordering fence only
            }
            __syncthreads();
        }

        // ---- stage h part of A = [h_t ; x_t] into swizzled LDS ----
        if (t == 0) {
            intx4 z = {0, 0, 0, 0};
            #pragma unroll
            for (int c4 = 0; c4 < 4; ++c4) {
                int byte = srow * (KTOT * 2) + sseg * 64 + c4 * 16;
                *reinterpret_cast<intx4*>(lds + (byte ^ sswz)) = z;
            }
        } else {
            const unsigned long long* src = reinterpret_cast<const unsigned long long*>(
                hbuf + (size_t)(t & 1) * B_ * H_ + (size_t)(b0 + srow) * H_ + sseg * 32);
            #pragma unroll
            for (int c4 = 0; c4 < 4; ++c4) {
                unsigned long long lov = __hip_atomic_load(src + c4 * 2,     __ATOMIC_RELAXED, __HIP_MEMORY_SCOPE_AGENT);
                unsigned long long hiv = __hip_atomic_load(src + c4 * 2 + 1, __ATOMIC_RELAXED, __HIP_MEMORY_SCOPE_AGENT);
                ull2 v; v.x = lov; v.y = hiv;
                int byte = srow * (KTOT * 2) + sseg * 64 + c4 * 16;
                *reinterpret_cast<ull2*>(lds + (byte ^ sswz)) = v;
            }
        }
        __syncthreads();

        // ---- MFMA: preact[16 x 32] for gate w, K = 640 ----
        floatx4 acc0 = {0.f, 0.f, 0.f, 0.f}, acc1 = {0.f, 0.f, 0.f, 0.f};
        #pragma unroll
        for (int ks = 0; ks < 20; ++ks) {
            int byte = (abase + ks * 64) ^ aswz;
            short8 a = *reinterpret_cast<const short8*>(lds + byte);
            acc0 = __builtin_amdgcn_mfma_f32_16x16x32_bf16(a, bfr0[ks], acc0, 0, 0, 0);
            acc1 = __builtin_amdgcn_mfma_f32_16x16x32_bf16(a, bfr1[ks], acc1, 0, 0, 0);
        }
        // C layout: col = lane&15, row = (lane>>4)*4 + r  (m89-verified)
        #pragma unroll
        for (int r = 0; r < 4; ++r) {
            pre[w][(lane >> 4) * 4 + r][(lane & 15)]      = acc0[r];
            pre[w][(lane >> 4) * 4 + r][16 + (lane & 15)] = acc1[r];
        }
        __syncthreads();

        // ---- elementwise LSTM cell; c-state lives in regs ----
        float hp[2];
        #pragma unroll
        for (int e = 0; e < 2; ++e) {
            int col = ep * 2 + e;
            float ag = pre[0][erow][col] + bge[e];
            float ai = pre[1][erow][col] + bie[e];
            float af = pre[2][erow][col] + bfe[e];
            float ao = pre[3][erow][col] + boe[e];
            float g = tanhf_(ag), ii = sigf(ai), f = sigf(af), o = sigf(ao);
            float c = g * ii + cst[e] * f;
            cst[e] = c;
            hp[e] = tanhf_(c) * o;
        }
        uint32_t packed = (uint32_t)f2bf(hp[0]) | ((uint32_t)f2bf(hp[1]) << 16);
        uint32_t* hdst = reinterpret_cast<uint32_t*>(
            hbuf + (size_t)((t + 1) & 1) * B_ * H_ + (size_t)(b0 + erow) * H_ + hcg0);
        __hip_atomic_store(hdst, packed, __ATOMIC_RELAXED, __HIP_MEMORY_SCOPE_AGENT);
        // sc1 stores: vmcnt(0) == visible at device coherence point (no L2 writeback needed)
        asm volatile("s_waitcnt vmcnt(0)" ::: "memory");
        __syncthreads();   // all threads past their waitcnt -> all h stores visible
        if (tid == 0)
            __hip_atomic_fetch_add(ctr + t + 1, 1, __ATOMIC_RELAXED, __HIP_MEMORY_SCOPE_AGENT);
        // next iteration's t>0 wait-barrier protects hx from early overwrite
    }
}

// ---- final projection: out[b][c] = h_T[b] . wph[:,c] + bp[c] ----
// hbuf was written with cache-bypassing (sc1) stores; read it the same way so a
// stale L2 line on a different XCD can never be observed.
__global__ void k_proj(const uint16_t* __restrict__ hb0, const float* __restrict__ wph,
                       const float* __restrict__ bp, float* __restrict__ out) {
    int b = blockIdx.x, lane = threadIdx.x;     // 64 threads
    const uint32_t* hrow = reinterpret_cast<const uint32_t*>(hb0 + (size_t)b * H_);
    float p[C_];
    #pragma unroll
    for (int c = 0; c < C_; ++c) p[c] = 0.f;
    #pragma unroll
    for (int q = 0; q < 4; ++q) {
        int k2 = lane + q * 64;                 // uint32 index 0..255 -> elems 2k2, 2k2+1
        uint32_t u = __hip_atomic_load(hrow + k2, __ATOMIC_RELAXED, __HIP_MEMORY_SCOPE_AGENT);
        float h0 = bf2f((uint16_t)(u & 0xFFFFu));
        float h1 = bf2f((uint16_t)(u >> 16));
        #pragma unroll
        for (int c = 0; c < C_; ++c)
            p[c] += h0 * wph[(size_t)(2 * k2) * C_ + c] + h1 * wph[(size_t)(2 * k2 + 1) * C_ + c];
    }
    #pragma unroll
    for (int c = 0; c < C_; ++c) {
        float v = p[c];
        #pragma unroll
        for (int off = 32; off; off >>= 1) v += __shfl_down(v, off, 64);
        if (lane == 0) out[(size_t)b * C_ + c] = v + bp[c];
    }
}

extern "C" void kernel_launch(void* const* d_in, const int* in_sizes, int n_in,
                              void* d_out, int out_size, void* d_ws, size_t ws_size,
                              hipStream_t stream) {
    const float* x   = (const float*)d_in[0];
    const float* wgx = (const float*)d_in[1];
    const float* wgh = (const float*)d_in[2];
    const float* bg  = (const float*)d_in[3];
    const float* wix = (const float*)d_in[4];
    const float* wih = (const float*)d_in[5];
    const float* bi  = (const float*)d_in[6];
    const float* wfx = (const float*)d_in[7];
    const float* wfh = (const float*)d_in[8];
    const float* bf  = (const float*)d_in[9];
    const float* wox = (const float*)d_in[10];
    const float* woh = (const float*)d_in[11];
    const float* bo  = (const float*)d_in[12];
    const float* wph = (const float*)d_in[13];
    const float* bp  = (const float*)d_in[14];

    if (ws_size < WS_NEED) return;  // fail loud (wrong output) rather than corrupt

    char* ws = (char*)d_ws;
    uint16_t* xbp = (uint16_t*)(ws + OFF_XB);
    uint16_t* wcp = (uint16_t*)(ws + OFF_WC);
    uint16_t* hbp = (uint16_t*)(ws + OFF_HB);
    int*      ctp = (int*)(ws + OFF_CT);

    hipMemsetAsync(ctp, 0, SZ_CT, stream);
    k_cvt_x<<<(B_ * T_ * D_) / (256 * 4), 256, 0, stream>>>(x, xbp);
    k_build_w<<<4 * H_, 256, 0, stream>>>(wgh, wih, wfh, woh, wgx, wix, wfx, wox, wcp);
    k_lstm<<<256, 256, 0, stream>>>(xbp, wcp, bg, bi, bf, bo, hbp, ctp);
    k_proj<<<B_, 64, 0, stream>>>(hbp /* parity 0 holds h_T */, wph, bp, (float*)d_out);
}

// Round 8
// 1344.785 us; speedup vs baseline: 2.1813x; 1.2046x over previous
//
#include <hip/hip_runtime.h>
#include <hip/hip_bf16.h>
#include <stdint.h>

typedef __attribute__((ext_vector_type(8))) short short8;
typedef __attribute__((ext_vector_type(4))) float floatx4;
typedef __attribute__((ext_vector_type(4))) int intx4;
typedef __attribute__((ext_vector_type(4))) unsigned int uintx4;
typedef __attribute__((ext_vector_type(4))) unsigned short ushort4v;

#define DEVI __device__ __forceinline__

// ---- problem sizes ----
constexpr int B_ = 256, T_ = 512, D_ = 128, H_ = 512, C_ = 10;
constexpr int KTOT = H_ + D_;       // 640: k = [h(512) ; x(128)]
constexpr int RG = 16;              // batch rows per group
constexpr int NBG = 16;             // batch groups
constexpr int NCG = 16;             // column groups
constexpr int HCW = 32;             // h-cols per WG

// ---- workspace layout (bytes) ----
constexpr size_t OFF_XB = 0;
constexpr size_t SZ_XB  = (size_t)B_ * T_ * D_ * 2;          // x in bf16
constexpr size_t OFF_WC = OFF_XB + SZ_XB;
constexpr size_t SZ_WC  = (size_t)4 * H_ * KTOT * 2;         // Wcomb[4*H][640] bf16
constexpr size_t OFF_HB = OFF_WC + SZ_WC;
constexpr size_t SZ_HB  = (size_t)2 * B_ * H_ * 2;           // h double buffer bf16
constexpr size_t OFF_FL = OFF_HB + SZ_HB;
constexpr size_t SZ_FL  = (size_t)NBG * NCG * 64;            // flags: 64B apart (no RMW)
constexpr size_t WS_NEED = OFF_FL + SZ_FL;

DEVI uint16_t f2bf(float f) {
    uint32_t u = __builtin_bit_cast(uint32_t, f);
    u += 0x7FFFu + ((u >> 16) & 1u);
    return (uint16_t)(u >> 16);
}
DEVI float bf2f(uint16_t u) {
    return __builtin_bit_cast(float, (uint32_t)u << 16);
}
DEVI float sigf(float x)  { return 1.0f / (1.0f + __expf(-x)); }
DEVI float tanhf_(float x){ return 1.0f - 2.0f / (1.0f + __expf(2.0f * x)); }

// ---- prep: x fp32 -> bf16 ----
__global__ void k_cvt_x(const float* __restrict__ x, uint16_t* __restrict__ xb) {
    int i = (blockIdx.x * 256 + threadIdx.x) * 4;   // total B*T*D = 16777216
    float4 v = *reinterpret_cast<const float4*>(x + i);
    ushort4v o;
    o.x = f2bf(v.x); o.y = f2bf(v.y); o.z = f2bf(v.z); o.w = f2bf(v.w);
    *reinterpret_cast<ushort4v*>(xb + i) = o;
}

// ---- prep: build combined transposed bf16 weights Wcomb[n'=g*512+n][k] ----
__global__ void k_build_w(const float* __restrict__ wgh, const float* __restrict__ wih,
                          const float* __restrict__ wfh, const float* __restrict__ woh,
                          const float* __restrict__ wgx, const float* __restrict__ wix,
                          const float* __restrict__ wfx, const float* __restrict__ wox,
                          uint16_t* __restrict__ wc) {
    int np = blockIdx.x;            // 0..2047
    int g = np >> 9, n = np & 511;
    const float* wh = (g == 0) ? wgh : (g == 1) ? wih : (g == 2) ? wfh : woh;
    const float* wx = (g == 0) ? wgx : (g == 1) ? wix : (g == 2) ? wfx : wox;
    for (int k = threadIdx.x; k < KTOT; k += 256) {
        float v = (k < H_) ? wh[(size_t)k * H_ + n] : wx[(size_t)(k - H_) * H_ + n];
        wc[(size_t)np * KTOT + k] = f2bf(v);
    }
}

// Opaque 16B weight load (kept resident in the unified VGPR/AGPR file)
#define WLOAD(dst, base, IMM) \
    asm volatile("global_load_dwordx4 %0, %1, off offset:" #IMM \
                 : "=v"(dst) : "v"(base))
#define WLOAD20(arr, base) \
    WLOAD(arr[0],  base, 0);    WLOAD(arr[1],  base, 64);   \
    WLOAD(arr[2],  base, 128);  WLOAD(arr[3],  base, 192);  \
    WLOAD(arr[4],  base, 256);  WLOAD(arr[5],  base, 320);  \
    WLOAD(arr[6],  base, 384);  WLOAD(arr[7],  base, 448);  \
    WLOAD(arr[8],  base, 512);  WLOAD(arr[9],  base, 576);  \
    WLOAD(arr[10], base, 640);  WLOAD(arr[11], base, 704);  \
    WLOAD(arr[12], base, 768);  WLOAD(arr[13], base, 832);  \
    WLOAD(arr[14], base, 896);  WLOAD(arr[15], base, 960);  \
    WLOAD(arr[16], base, 1024); WLOAD(arr[17], base, 1088); \
    WLOAD(arr[18], base, 1152); WLOAD(arr[19], base, 1216)

// device-coherent 16B load (h exchange; per-4B consistency is sufficient)
#define HLOAD(dst, base, IMM) \
    asm volatile("global_load_dwordx4 %0, %1, off offset:" #IMM " sc0 sc1" \
                 : "=v"(dst) : "v"(base) : "memory")

// ---- main recurrent kernel ----
// WG = 16 batch rows x 32 h-cols (4 waves, one gate per wave; pre[] LDS gate
// exchange). Sync per step (validated round-2 semantics, all device-scope):
//   producer: store h (sc1) -> s_waitcnt vmcnt(0) -> barrier -> store OWN flag
//   consumer: wave0 lanes 0-15 poll the 16 per-cg flags in parallel (+ballot)
// Flags are plain stores 64B apart (no RMW serialization at the MALL).
__global__ __launch_bounds__(256, 1) void k_lstm(
    const uint16_t* __restrict__ xb,   // [B][T][D] bf16
    const uint16_t* __restrict__ wc,   // [4H][KTOT] bf16
    const float* __restrict__ bgp, const float* __restrict__ bip,
    const float* __restrict__ bfp, const float* __restrict__ bop,
    uint16_t* hbuf,                    // [2][B][H] bf16
    int* flags)                        // [NBG][NCG] ints, 64B apart
{
    __shared__ __align__(16) short hx[RG * KTOT];                 // 20 KB, XOR-swizzled
    __shared__ float pre[4][RG][HCW + 2];                         // stride 34: 2-way banks

    const int tid  = threadIdx.x;
    const int lane = tid & 63;
    const int w    = tid >> 6;          // wave id == gate id (g,i,f,o)
    const int bid  = blockIdx.x;
    // keep each batch-group's 16 WGs on one XCD (perf heuristic only)
    const int xcd = bid & 7, j = bid >> 3;
    const int bg = xcd * 2 + (j >> 4);
    const int cg = j & 15;
    const int b0  = bg * RG;
    const int hc0 = cg * HCW;

    // ---- load this wave's weight slice into registers (resident all run) ----
    short8 bfr0[20], bfr1[20];
    {
        const int lcol = lane & 15, kgrp = lane >> 4;
        const uint16_t* src0 = wc + (size_t)(w * H_ + hc0 + 0  + lcol) * KTOT + kgrp * 8;
        const uint16_t* src1 = wc + (size_t)(w * H_ + hc0 + 16 + lcol) * KTOT + kgrp * 8;
        WLOAD20(bfr0, src0);
        WLOAD20(bfr1, src1);
        asm volatile("s_waitcnt vmcnt(0)" ::: "memory");
    }

    // ---- elementwise thread mapping: (row, col pair) fixed for whole run ----
    const int erow = tid >> 4;          // 0..15
    const int epr  = tid & 15;          // 0..15 -> cols epr*2, epr*2+1
    const int hcg0 = hc0 + epr * 2;
    float bge[2], bie[2], bfe[2], boe[2], cst[2] = {0.f, 0.f};
    #pragma unroll
    for (int e = 0; e < 2; ++e) {
        bge[e] = bgp[hcg0 + e]; bie[e] = bip[hcg0 + e];
        bfe[e] = bfp[hcg0 + e]; boe[e] = bop[hcg0 + e];
    }

    // staging mapping: thread -> (row, 64B segment)
    const int srow = tid >> 4, sseg = tid & 15;
    const int sswz = (srow & 7) << 4;
    // A-fragment base (mfma 16x16x32: row = lane&15, k = (lane>>4)*8 + j)
    const int arow = lane & 15, akg = lane >> 4;
    const int abase = arow * (KTOT * 2) + akg * 16;
    const int aswz  = (arow & 7) << 4;

    int* fbase = flags + bg * NCG * 16;   // 16 ints (=64B) per flag slot
    char* lds = (char*)hx;

    for (int t = 0; t < T_; ++t) {
        // ---- stage x part (cols 512..639) BEFORE the wait (no h dependence;
        //      prev step's LDS readers passed the post-store barrier) ----
        {
            const short8 xv = *reinterpret_cast<const short8*>(
                xb + ((size_t)(b0 + srow) * T_ + t) * D_ + sseg * 8);
            int byte = srow * (KTOT * 2) + H_ * 2 + sseg * 16;
            *reinterpret_cast<short8*>(lds + (byte ^ sswz)) = xv;
        }

        // ---- wait for h_t from all 16 column groups (parallel flag poll) ----
        if (t > 0) {
            if (w == 0) {
                int it = 0;
                for (;;) {
                    int f = t;
                    if (lane < NCG)
                        f = __hip_atomic_load(fbase + lane * 16, __ATOMIC_RELAXED,
                                              __HIP_MEMORY_SCOPE_AGENT);
                    if (__ballot(f == t) == ~0ull) break;
                    if (++it > (1 << 22)) break;   // fail loud, not hang
                    __builtin_amdgcn_s_sleep(1);
                }
                asm volatile("" ::: "memory");     // compiler reordering fence only
            }
            __syncthreads();
        }

        // ---- stage h part of A = [h_t ; x_t] into swizzled LDS ----
        if (t == 0) {
            intx4 z = {0, 0, 0, 0};
            #pragma unroll
            for (int c4 = 0; c4 < 4; ++c4) {
                int byte = srow * (KTOT * 2) + sseg * 64 + c4 * 16;
                *reinterpret_cast<intx4*>(lds + (byte ^ sswz)) = z;
            }
        } else {
            const uint32_t* src = reinterpret_cast<const uint32_t*>(
                hbuf + (size_t)(t & 1) * B_ * H_ + (size_t)(b0 + srow) * H_ + sseg * 32);
            uintx4 v0, v1, v2, v3;
            HLOAD(v0, src, 0);  HLOAD(v1, src, 16);
            HLOAD(v2, src, 32); HLOAD(v3, src, 48);
            asm volatile("s_waitcnt vmcnt(0)" ::: "memory");
            #pragma unroll
            for (int c4 = 0; c4 < 4; ++c4) {
                uintx4 v = (c4 == 0) ? v0 : (c4 == 1) ? v1 : (c4 == 2) ? v2 : v3;
                int byte = srow * (KTOT * 2) + sseg * 64 + c4 * 16;
                *reinterpret_cast<uintx4*>(lds + (byte ^ sswz)) = v;
            }
        }
        __syncthreads();

        // ---- MFMA: preact[16 x 32] for gate w, K = 640 ----
        floatx4 acc0 = {0.f, 0.f, 0.f, 0.f}, acc1 = {0.f, 0.f, 0.f, 0.f};
        #pragma unroll
        for (int ks = 0; ks < 20; ++ks) {
            int byte = (abase + ks * 64) ^ aswz;
            short8 a = *reinterpret_cast<const short8*>(lds + byte);
            acc0 = __builtin_amdgcn_mfma_f32_16x16x32_bf16(a, bfr0[ks], acc0, 0, 0, 0);
            acc1 = __builtin_amdgcn_mfma_f32_16x16x32_bf16(a, bfr1[ks], acc1, 0, 0, 0);
        }
        // C layout: col = lane&15, row = (lane>>4)*4 + r  (m89-verified)
        #pragma unroll
        for (int r = 0; r < 4; ++r) {
            pre[w][(lane >> 4) * 4 + r][(lane & 15)]      = acc0[r];
            pre[w][(lane >> 4) * 4 + r][16 + (lane & 15)] = acc1[r];
        }
        __syncthreads();

        // ---- elementwise LSTM cell; c-state lives in regs ----
        float hp[2];
        #pragma unroll
        for (int e = 0; e < 2; ++e) {
            int col = epr * 2 + e;
            float ag = pre[0][erow][col] + bge[e];
            float ai = pre[1][erow][col] + bie[e];
            float af = pre[2][erow][col] + bfe[e];
            float ao = pre[3][erow][col] + boe[e];
            float g = tanhf_(ag), ii = sigf(ai), f = sigf(af), o = sigf(ao);
            float c = g * ii + cst[e] * f;
            cst[e] = c;
            hp[e] = tanhf_(c) * o;
        }
        uint32_t packed = (uint32_t)f2bf(hp[0]) | ((uint32_t)f2bf(hp[1]) << 16);
        uint32_t* hdst = reinterpret_cast<uint32_t*>(
            hbuf + (size_t)((t + 1) & 1) * B_ * H_ + (size_t)(b0 + erow) * H_ + hcg0);
        __hip_atomic_store(hdst, packed, __ATOMIC_RELAXED, __HIP_MEMORY_SCOPE_AGENT);
        // drain own h stores to the device coherence point, then signal
        asm volatile("s_waitcnt vmcnt(0)" ::: "memory");
        __syncthreads();   // all threads past their waitcnt -> all h stores visible
        if (tid == 0)
            __hip_atomic_store(fbase + cg * 16, t + 1, __ATOMIC_RELAXED,
                               __HIP_MEMORY_SCOPE_AGENT);
        // next iteration's wait-barrier protects hx from early overwrite
    }
}

// ---- final projection: out[b][c] = h_T[b] . wph[:,c] + bp[c] ----
__global__ void k_proj(const uint16_t* __restrict__ hb0, const float* __restrict__ wph,
                       const float* __restrict__ bp, float* __restrict__ out) {
    int b = blockIdx.x, lane = threadIdx.x;     // 64 threads
    const uint32_t* hrow = reinterpret_cast<const uint32_t*>(hb0 + (size_t)b * H_);
    float p[C_];
    #pragma unroll
    for (int c = 0; c < C_; ++c) p[c] = 0.f;
    #pragma unroll
    for (int q = 0; q < 4; ++q) {
        int k2 = lane + q * 64;                 // uint32 index 0..255 -> elems 2k2, 2k2+1
        uint32_t u = __hip_atomic_load(hrow + k2, __ATOMIC_RELAXED, __HIP_MEMORY_SCOPE_AGENT);
        float h0 = bf2f((uint16_t)(u & 0xFFFFu));
        float h1 = bf2f((uint16_t)(u >> 16));
        #pragma unroll
        for (int c = 0; c < C_; ++c)
            p[c] += h0 * wph[(size_t)(2 * k2) * C_ + c] + h1 * wph[(size_t)(2 * k2 + 1) * C_ + c];
    }
    #pragma unroll
    for (int c = 0; c < C_; ++c) {
        float v = p[c];
        #pragma unroll
        for (int off = 32; off; off >>= 1) v += __shfl_down(v, off, 64);
        if (lane == 0) out[(size_t)b * C_ + c] = v + bp[c];
    }
}

extern "C" void kernel_launch(void* const* d_in, const int* in_sizes, int n_in,
                              void* d_out, int out_size, void* d_ws, size_t ws_size,
                              hipStream_t stream) {
    const float* x   = (const float*)d_in[0];
    const float* wgx = (const float*)d_in[1];
    const float* wgh = (const float*)d_in[2];
    const float* bg  = (const float*)d_in[3];
    const float* wix = (const float*)d_in[4];
    const float* wih = (const float*)d_in[5];
    const float* bi  = (const float*)d_in[6];
    const float* wfx = (const float*)d_in[7];
    const float* wfh = (const float*)d_in[8];
    const float* bf  = (const float*)d_in[9];
    const float* wox = (const float*)d_in[10];
    const float* woh = (const float*)d_in[11];
    const float* bo  = (const float*)d_in[12];
    const float* wph = (const float*)d_in[13];
    const float* bp  = (const float*)d_in[14];

    if (ws_size < WS_NEED) return;  // fail loud (wrong output) rather than corrupt

    char* ws = (char*)d_ws;
    uint16_t* xbp = (uint16_t*)(ws + OFF_XB);
    uint16_t* wcp = (uint16_t*)(ws + OFF_WC);
    uint16_t* hbp = (uint16_t*)(ws + OFF_HB);
    int*      flp = (int*)(ws + OFF_FL);

    hipMemsetAsync(flp, 0, SZ_FL, stream);
    k_cvt_x<<<(B_ * T_ * D_) / (256 * 4), 256, 0, stream>>>(x, xbp);
    k_build_w<<<4 * H_, 256, 0, stream>>>(wgh, wih, wfh, woh, wgx, wix, wfx, wox, wcp);
    k_lstm<<<256, 256, 0, stream>>>(xbp, wcp, bg, bi, bf, bo, hbp, flp);
    k_proj<<<B_, 64, 0, stream>>>(hbp /* parity 0 holds h_T */, wph, bp, (float*)d_out);
}